// Round 1
// baseline (429.065 us; speedup 1.0000x reference)
//
#include <hip/hip_runtime.h>

// Problem constants (B,T,C,H fixed by the reference).
constexpr int Bn = 4, Tn = 2048, Cn = 1024, Hn = 16, Dn = 64;

typedef __attribute__((ext_vector_type(8))) short short8;
typedef __attribute__((ext_vector_type(4))) float floatx4;

#define DEVFN __device__ __forceinline__

// RTNE float -> bf16 raw bits (inputs are finite; no NaN handling needed).
DEVFN short f2bf(float f) {
  unsigned u = __builtin_bit_cast(unsigned, f);
  u += 0x7fffu + ((u >> 16) & 1u);
  return (short)(u >> 16);
}

DEVFN floatx4 mfma16(short8 a, short8 b, floatx4 c) {
  return __builtin_amdgcn_mfma_f32_16x16x32_bf16(a, b, c, 0, 0, 0);
}

// Async global->LDS, 16B per lane. LDS dest is wave-uniform base + lane*16,
// which our tid*16 layout satisfies exactly.
DEVFN void gld_lds16(const void* g, void* l) {
  __builtin_amdgcn_global_load_lds(
      (const __attribute__((address_space(1))) unsigned*)g,
      (__attribute__((address_space(3))) unsigned*)l, 16, 0, 0);
}

// ---------------------------------------------------------------- cast fp32->bf16
__global__ __launch_bounds__(256) void cast_bf16_kernel(
    const float* __restrict__ in, short* __restrict__ out, int n8) {
  int i = blockIdx.x * 256 + threadIdx.x;
  if (i >= n8) return;
  const floatx4* p = (const floatx4*)in + (size_t)i * 2;
  floatx4 a = p[0], b = p[1];
  short8 r;
  r[0] = f2bf(a[0]); r[1] = f2bf(a[1]); r[2] = f2bf(a[2]); r[3] = f2bf(a[3]);
  r[4] = f2bf(b[0]); r[5] = f2bf(b[1]); r[6] = f2bf(b[2]); r[7] = f2bf(b[3]);
  ((short8*)out)[i] = r;
}

// ---------------------------------------------------------------- GEMM  Y = A @ B^T
// A: [M,K] bf16 row-major.  Bw: [N,K] bf16 row-major (i.e. the weight as stored).
// MODE 0: QKV projection. cols [0,2048) -> qkb [M,2048]; cols [2048,3072) are V,
//         written TRANSPOSED into vtb[B][H][D][T] so attention can stage V^T with
//         vectorized loads (no LDS scatter-transpose needed).
// MODE 1: output projection: fp32 out + bias.
template <int MODE>
__global__ __launch_bounds__(256, 2) void gemm_bt(
    const short* __restrict__ A, const short* __restrict__ Bw, int M, int N, int K,
    short* __restrict__ qkb, short* __restrict__ vtb,
    const float* __restrict__ bias, float* __restrict__ fout) {
  __shared__ short As[128 * 32];
  __shared__ short Bs[128 * 32];
  const int tid = threadIdx.x;
  const int lane = tid & 63, wave = tid >> 6;
  const int l15 = lane & 15, quad = lane >> 4;
  const int wr = wave >> 1, wc = wave & 1;
  const int m0 = blockIdx.x * 128, n0 = blockIdx.y * 128;

  // Staging map: thread t covers LDS bytes [t*16, t*16+16) = row t/4, cols (t%4)*8..+8
  const int srow = tid >> 2;
  const int scol = (tid & 3) * 8;
  const short* Ag = A + (size_t)(m0 + srow) * K + scol;
  const short* Bg = Bw + (size_t)(n0 + srow) * K + scol;
  short* AsW = As + tid * 8;
  short* BsW = Bs + tid * 8;

  floatx4 acc[4][4] = {};

  for (int k0 = 0; k0 < K; k0 += 32) {
    gld_lds16(Ag + k0, AsW);
    gld_lds16(Ag + (size_t)64 * K + k0, AsW + 64 * 32);
    gld_lds16(Bg + k0, BsW);
    gld_lds16(Bg + (size_t)64 * K + k0, BsW + 64 * 32);
    __syncthreads();
    short8 af[4], bf[4];
#pragma unroll
    for (int i = 0; i < 4; ++i)
      af[i] = *(const short8*)(As + (wr * 64 + i * 16 + l15) * 32 + quad * 8);
#pragma unroll
    for (int i = 0; i < 4; ++i)
      bf[i] = *(const short8*)(Bs + (wc * 64 + i * 16 + l15) * 32 + quad * 8);
#pragma unroll
    for (int mi = 0; mi < 4; ++mi)
#pragma unroll
      for (int ni = 0; ni < 4; ++ni)
        acc[mi][ni] = mfma16(af[mi], bf[ni], acc[mi][ni]);
    __syncthreads();
  }

  // Epilogue. C/D layout: col = lane&15 (n), row = quad*4 + reg (m). [m89/m91]
#pragma unroll
  for (int mi = 0; mi < 4; ++mi) {
#pragma unroll
    for (int r = 0; r < 4; ++r) {
      const int row = m0 + wr * 64 + mi * 16 + quad * 4 + r;
#pragma unroll
      for (int ni = 0; ni < 4; ++ni) {
        const int col = n0 + wc * 64 + ni * 16 + l15;
        const float v = acc[mi][ni][r];
        if constexpr (MODE == 0) {
          const short bv = f2bf(v);
          if (col < 2 * Cn) {
            qkb[(size_t)row * (2 * Cn) + col] = bv;
          } else {
            const int hc = col - 2 * Cn;
            const int hh = hc >> 6, d = hc & 63;
            const int bb = row >> 11, t = row & (Tn - 1);
            vtb[((size_t)((bb * Hn + hh) * Dn + d)) * Tn + t] = bv;
          }
        } else {
          fout[(size_t)row * N + col] = v + bias[col];
        }
      }
    }
  }
}

// ---------------------------------------------------------------- flash attention
// Block = 4 waves = one 64-row Q tile of one (b,h). Wave w owns Q rows
// q0+w*16 .. +15. KV tile = 64. Online softmax, fp32 state; P round-trips
// through per-wave LDS (C-layout -> A-operand layout, m120 pattern).
__global__ __launch_bounds__(256, 2) void attn_kernel(
    const short* __restrict__ qk, const short* __restrict__ vt,
    short* __restrict__ att) {
  __shared__ short Ks[64 * 72];     // K tile  [j][d], +8 pad -> 2-way banks (free)
  __shared__ short Vs[64 * 72];     // V^T tile [d][j], +8 pad
  __shared__ short Ps[4][16 * 72];  // per-wave P tile [i][j], +8 pad

  const int qt = blockIdx.x;  // 0..31
  const int bh = blockIdx.y;  // 0..63
  const int b = bh >> 4, h = bh & 15;
  const int tid = threadIdx.x;
  const int lane = tid & 63, wave = tid >> 6;
  const int l15 = lane & 15, quad = lane >> 4;
  const int q0 = qt * 64;

  const short* qbase = qk + (size_t)(b * Tn) * 2048 + h * 64;
  const short* kbase = qk + (size_t)(b * Tn) * 2048 + 1024 + h * 64;
  const short* vbase = vt + (size_t)(bh * 64) * Tn;  // rows d, stride T

  // Q fragments held in registers for the whole block: A[m=l15][k=quad*8+j]
  const int qr = q0 + wave * 16 + l15;
  const short8 qf0 = *(const short8*)(qbase + (size_t)qr * 2048 + quad * 8);
  const short8 qf1 = *(const short8*)(qbase + (size_t)qr * 2048 + 32 + quad * 8);

  floatx4 o[4] = {};
  float m_run[4], l_run[4];
  int qi[4];
#pragma unroll
  for (int r = 0; r < 4; ++r) {
    m_run[r] = -INFINITY;
    l_run[r] = 0.f;
    qi[r] = q0 + wave * 16 + quad * 4 + r;
  }

  const int sr = tid >> 3;        // staging row 0..31 (+32 second pass)
  const int sc = (tid & 7) * 8;   // staging col

  for (int jt = 0; jt <= qt; ++jt) {
    const int j0 = jt * 64;
    __syncthreads();  // previous iteration's PV reads done before restage
#pragma unroll
    for (int it = 0; it < 2; ++it) {
      const int rr = sr + it * 32;
      *(short8*)(Ks + rr * 72 + sc) =
          *(const short8*)(kbase + (size_t)(j0 + rr) * 2048 + sc);
      *(short8*)(Vs + rr * 72 + sc) =
          *(const short8*)(vbase + (size_t)rr * Tn + j0 + sc);
    }
    __syncthreads();

    // S = Q K^T  (4 col-tiles x 2 K-steps = 8 MFMAs)
    floatx4 sa[4] = {};
#pragma unroll
    for (int nj = 0; nj < 4; ++nj) {
      short8 kf = *(const short8*)(Ks + (nj * 16 + l15) * 72 + quad * 8);
      sa[nj] = mfma16(qf0, kf, sa[nj]);
    }
#pragma unroll
    for (int nj = 0; nj < 4; ++nj) {
      short8 kf = *(const short8*)(Ks + (nj * 16 + l15) * 72 + 32 + quad * 8);
      sa[nj] = mfma16(qf1, kf, sa[nj]);
    }

    // scale + causal mask. Lane holds S[i=quad*4+r][j=j0+nj*16+l15].
    float sv[4][4];
#pragma unroll
    for (int nj = 0; nj < 4; ++nj) {
      const int jc = j0 + nj * 16 + l15;
#pragma unroll
      for (int r = 0; r < 4; ++r) {
        const float x = sa[nj][r] * 0.125f;  // 1/sqrt(64)
        sv[nj][r] = (jc > qi[r]) ? -INFINITY : x;
      }
    }

    // online softmax; row reductions across the 16 lanes of each quad group
    float alpha[4];
#pragma unroll
    for (int r = 0; r < 4; ++r) {
      float t = fmaxf(fmaxf(sv[0][r], sv[1][r]), fmaxf(sv[2][r], sv[3][r]));
      t = fmaxf(t, __shfl_xor(t, 1));
      t = fmaxf(t, __shfl_xor(t, 2));
      t = fmaxf(t, __shfl_xor(t, 4));
      t = fmaxf(t, __shfl_xor(t, 8));
      const float mn = fmaxf(m_run[r], t);  // finite from tile 0 on
      alpha[r] = __expf(m_run[r] - mn);
      m_run[r] = mn;
#pragma unroll
      for (int nj = 0; nj < 4; ++nj) sv[nj][r] = __expf(sv[nj][r] - mn);
      float s = sv[0][r] + sv[1][r] + sv[2][r] + sv[3][r];
      s += __shfl_xor(s, 1);
      s += __shfl_xor(s, 2);
      s += __shfl_xor(s, 4);
      s += __shfl_xor(s, 8);
      l_run[r] = l_run[r] * alpha[r] + s;
    }
#pragma unroll
    for (int nd = 0; nd < 4; ++nd) {
      o[nd][0] *= alpha[0];
      o[nd][1] *= alpha[1];
      o[nd][2] *= alpha[2];
      o[nd][3] *= alpha[3];
    }

    // P: C-layout regs -> LDS [i][j] -> A-operand fragments
    short* pw = Ps[wave];
#pragma unroll
    for (int nj = 0; nj < 4; ++nj)
#pragma unroll
      for (int r = 0; r < 4; ++r)
        pw[(quad * 4 + r) * 72 + nj * 16 + l15] = f2bf(sv[nj][r]);
    __syncthreads();  // makes P visible across lanes (and is block-uniform)

    const short8 pf0 = *(const short8*)(pw + l15 * 72 + quad * 8);
    const short8 pf1 = *(const short8*)(pw + l15 * 72 + 32 + quad * 8);
#pragma unroll
    for (int nd = 0; nd < 4; ++nd) {
      short8 vf = *(const short8*)(Vs + (nd * 16 + l15) * 72 + quad * 8);
      o[nd] = mfma16(pf0, vf, o[nd]);
    }
#pragma unroll
    for (int nd = 0; nd < 4; ++nd) {
      short8 vf = *(const short8*)(Vs + (nd * 16 + l15) * 72 + 32 + quad * 8);
      o[nd] = mfma16(pf1, vf, o[nd]);
    }
  }

  float inv[4];
#pragma unroll
  for (int r = 0; r < 4; ++r) inv[r] = 1.0f / l_run[r];
#pragma unroll
  for (int nd = 0; nd < 4; ++nd)
#pragma unroll
    for (int r = 0; r < 4; ++r)
      att[(size_t)(b * Tn + qi[r]) * Cn + h * 64 + nd * 16 + l15] =
          f2bf(o[nd][r] * inv[r]);
}

// ---------------------------------------------------------------- launch
extern "C" void kernel_launch(void* const* d_in, const int* in_sizes, int n_in,
                              void* d_out, int out_size, void* d_ws,
                              size_t ws_size, hipStream_t stream) {
  const float* x = (const float*)d_in[0];      // [B,T,C]
  const float* w_qkv = (const float*)d_in[1];  // [3C,C]
  const float* w_out = (const float*)d_in[2];  // [C,C]
  const float* b_out = (const float*)d_in[3];  // [C]
  float* out = (float*)d_out;                  // [B,T,C] fp32

  // Workspace layout (75.5 MB total):
  short* xb = (short*)d_ws;                      // 8192*1024  x bf16
  short* wqb = xb + (size_t)8192 * 1024;         // 3072*1024  w_qkv bf16
  short* wob = wqb + (size_t)3072 * 1024;        // 1024*1024  w_out bf16
  short* qkb = wob + (size_t)1024 * 1024;        // 8192*2048  q|k bf16
  short* vtb = qkb + (size_t)8192 * 2048;        // 64*64*2048 v transposed
  short* att = xb;  // x is dead after GEMM1; reuse for attention output

  cast_bf16_kernel<<<dim3(8192 * 1024 / 8 / 256), 256, 0, stream>>>(
      x, xb, 8192 * 1024 / 8);
  cast_bf16_kernel<<<dim3(3072 * 1024 / 8 / 256), 256, 0, stream>>>(
      w_qkv, wqb, 3072 * 1024 / 8);
  cast_bf16_kernel<<<dim3(1024 * 1024 / 8 / 256), 256, 0, stream>>>(
      w_out, wob, 1024 * 1024 / 8);

  // QKV projection: M=8192, N=3072, K=1024
  gemm_bt<0><<<dim3(64, 24), 256, 0, stream>>>(xb, wqb, 8192, 3072, 1024, qkb,
                                               vtb, nullptr, nullptr);
  // Flash attention: grid (q-tiles, b*h)
  attn_kernel<<<dim3(32, 64), 256, 0, stream>>>(qkb, vtb, att);
  // Output projection: M=8192, N=1024, K=1024, +bias, fp32 out
  gemm_bt<1><<<dim3(64, 8), 256, 0, stream>>>(att, wob, 8192, 1024, 1024,
                                              nullptr, nullptr, b_out, out);
}